// Round 1
// baseline (767.517 us; speedup 1.0000x reference)
//
#include <hip/hip_runtime.h>

#define CC   1024
#define C2   2048
#define HH   64
#define WW   64
#define HW   4096
#define MOUT 2048
#define NB   4
#define LP   40   // GEMM LDS pitch in bf16 elems (80B: 16B-aligned, 2-way bank alias = free)

typedef short  short8  __attribute__((ext_vector_type(8)));
typedef float  floatx4 __attribute__((ext_vector_type(4)));

static __device__ __forceinline__ unsigned short f2bf(float f) {
  unsigned int u = __builtin_bit_cast(unsigned int, f);
  u = u + 0x7FFFu + ((u >> 16) & 1u);   // RNE truncate to bf16
  return (unsigned short)(u >> 16);
}

// ---------------------------------------------------------------------------
// Kernel 1: 3x3 conv (2048 -> 2 channels), SAME padding. Channel-split with
// atomicAdd accumulation. Block = (chunk of 256 ch) x (8 output rows) x b.
// ---------------------------------------------------------------------------
__global__ __launch_bounds__(256)
void conv_off(const float* __restrict__ refer, const float* __restrict__ sup,
              const float* __restrict__ woff, float* __restrict__ off)
{
  const int chunk = blockIdx.x;          // 0..7  -> channels [chunk*256, +256)
  const int h0    = blockIdx.y * 8;      // output rows h0..h0+7
  const int b     = blockIdx.z;
  const int tid   = threadIdx.x;

  __shared__ float lds[10 * 66];         // 10 input rows, w padded -1/+1
  for (int i = tid; i < 10 * 66; i += 256) lds[i] = 0.f;

  const int w   = tid & 63;
  const int r2  = tid >> 6;              // 0..3 (uniform per wave)
  const int ro0 = r2 * 2;                // this thread owns output rows ro0, ro0+1

  float a00 = 0.f, a01 = 0.f, a10 = 0.f, a11 = 0.f;

  const int cbase = chunk * 256;
  for (int ci = 0; ci < 256; ci++) {
    const int cc = cbase + ci;
    const float* plane = (cc < CC) ? (refer + ((size_t)b * CC + cc) * HW)
                                   : (sup   + ((size_t)b * CC + (cc - CC)) * HW);
    __syncthreads();                     // protect previous iter's LDS reads
    for (int i = tid; i < 640; i += 256) {
      const int r = i >> 6, x = i & 63;
      const int gy = h0 - 1 + r;
      lds[r * 66 + 1 + x] = (gy >= 0 && gy < HH) ? plane[gy * WW + x] : 0.f;
    }
    __syncthreads();

    // 18 wave-uniform weight loads -> scalar loads
    const float* wp0 = woff + (size_t)cc * 9;
    const float* wp1 = woff + (size_t)(C2 + cc) * 9;
    float wv0[9], wv1[9];
#pragma unroll
    for (int k = 0; k < 9; k++) { wv0[k] = wp0[k]; wv1[k] = wp1[k]; }

    // 4 LDS rows x 3 taps cover both owned output rows
    float v[4][3];
#pragma unroll
    for (int r = 0; r < 4; r++)
#pragma unroll
      for (int x = 0; x < 3; x++)
        v[r][x] = lds[(ro0 + r) * 66 + w + x];

#pragma unroll
    for (int ky = 0; ky < 3; ky++)
#pragma unroll
      for (int kx = 0; kx < 3; kx++) {
        const float w0 = wv0[ky * 3 + kx], w1 = wv1[ky * 3 + kx];
        a00 += v[ky][kx]     * w0;
        a01 += v[ky][kx]     * w1;
        a10 += v[ky + 1][kx] * w0;
        a11 += v[ky + 1][kx] * w1;
      }
  }

  const int h_0 = h0 + ro0, h_1 = h0 + ro0 + 1;
  atomicAdd(&off[((b * 2 + 0) * HH + h_0) * WW + w], a00);
  atomicAdd(&off[((b * 2 + 1) * HH + h_0) * WW + w], a01);
  atomicAdd(&off[((b * 2 + 0) * HH + h_1) * WW + w], a10);
  atomicAdd(&off[((b * 2 + 1) * HH + h_1) * WW + w], a11);
}

// ---------------------------------------------------------------------------
// Kernel 2: fp32 -> bf16 convert for w_def
// ---------------------------------------------------------------------------
__global__ __launch_bounds__(256)
void cvt_bf16(const float* __restrict__ src, unsigned short* __restrict__ dst, int n4)
{
  const int i = blockIdx.x * 256 + threadIdx.x;
  if (i < n4) {
    const float4 f = ((const float4*)src)[i];
    ushort4 u;
    u.x = f2bf(f.x); u.y = f2bf(f.y); u.z = f2bf(f.z); u.w = f2bf(f.w);
    ((ushort4*)dst)[i] = u;
  }
}

// ---------------------------------------------------------------------------
// Kernel 3: bilinear deform-sample sup_feat at (h+dy, w+dx), zero pad outside.
// Writes S_t[b][l][c] bf16 (k-innermost, i.e. the GEMM's B^T layout).
// Block = one image row (64 l) x all 1024 c, LDS transpose 64l x 64c tiles.
// ---------------------------------------------------------------------------
__global__ __launch_bounds__(256)
void sample_kern(const float* __restrict__ sup, const float* __restrict__ off,
                 const float* __restrict__ boff, unsigned short* __restrict__ St)
{
  const int h   = blockIdx.x;
  const int b   = blockIdx.y;
  const int tid = threadIdx.x;

  __shared__ float swy[64], swx[64];
  __shared__ int   sy0[64], sx0[64];
  __shared__ unsigned short tile[64 * 68];   // [c][l], pitch 68

  if (tid < 64) {
    const float dy = off[((b * 2 + 0) * HH + h) * WW + tid] + boff[0];
    const float dx = off[((b * 2 + 1) * HH + h) * WW + tid] + boff[1];
    const float py = dy + (float)h;
    const float px = dx + (float)tid;
    const float y0f = floorf(py), x0f = floorf(px);
    sy0[tid] = (int)y0f;  sx0[tid] = (int)x0f;
    swy[tid] = py - y0f;  swx[tid] = px - x0f;
  }
  __syncthreads();

  const int l   = tid & 63;
  const int cs0 = tid >> 6;
  const int y0 = sy0[l], x0 = sx0[l];
  const int y1 = y0 + 1, x1 = x0 + 1;
  const float wy1 = swy[l], wx1 = swx[l];
  const float wy0 = 1.f - wy1, wx0 = 1.f - wx1;
  const float vy0 = (y0 >= 0 && y0 < HH) ? 1.f : 0.f;
  const float vy1 = (y1 >= 0 && y1 < HH) ? 1.f : 0.f;
  const float vx0 = (x0 >= 0 && x0 < WW) ? 1.f : 0.f;
  const float vx1 = (x1 >= 0 && x1 < WW) ? 1.f : 0.f;
  const int cy0 = min(max(y0, 0), HH - 1), cy1 = min(max(y1, 0), HH - 1);
  const int cx0 = min(max(x0, 0), WW - 1), cx1 = min(max(x1, 0), WW - 1);
  const int i00 = cy0 * WW + cx0, i01 = cy0 * WW + cx1;
  const int i10 = cy1 * WW + cx0, i11 = cy1 * WW + cx1;
  const float w00 = wy0 * wx0 * vy0 * vx0;
  const float w01 = wy0 * wx1 * vy0 * vx1;
  const float w10 = wy1 * wx0 * vy1 * vx0;
  const float w11 = wy1 * wx1 * vy1 * vx1;

  const int cq  = tid & 15;
  const int ls0 = tid >> 4;
  unsigned short* stb = St + ((size_t)b * HW + h * 64) * CC;

  for (int ct = 0; ct < 16; ct++) {
    const int cb = ct * 64;
    // phase A: lanes across l (coalesced gathers), write tile[c][l]
    for (int cs = cs0; cs < 64; cs += 4) {
      const float* sp = sup + ((size_t)b * CC + cb + cs) * HW;
      const float v = w00 * sp[i00] + w01 * sp[i01] + w10 * sp[i10] + w11 * sp[i11];
      tile[cs * 68 + l] = f2bf(v);
    }
    __syncthreads();
    // phase B: lanes across c, coalesced ushort4 stores to S_t[l][c]
    for (int ls = ls0; ls < 64; ls += 16) {
      ushort4 pk;
      pk.x = tile[(cq * 4 + 0) * 68 + ls];
      pk.y = tile[(cq * 4 + 1) * 68 + ls];
      pk.z = tile[(cq * 4 + 2) * 68 + ls];
      pk.w = tile[(cq * 4 + 3) * 68 + ls];
      *(ushort4*)&stb[(size_t)ls * CC + cb + cq * 4] = pk;
    }
    __syncthreads();
  }
}

// ---------------------------------------------------------------------------
// Kernel 4: bf16 MFMA GEMM. out[b][m][n] = sum_k A[m][k] * Bt[b][n][k].
// 128x128 block tile, BK=32, 4 waves each 64x64 (4x4 of 16x16x32 MFMA).
// ---------------------------------------------------------------------------
__global__ __launch_bounds__(256)
void gemm_bt(const unsigned short* __restrict__ A,
             const unsigned short* __restrict__ Bt,
             float* __restrict__ C)
{
  const int bb = blockIdx.z;
  const int n0 = blockIdx.x * 128;
  const int m0 = blockIdx.y * 128;
  const unsigned short* Bb = Bt + (size_t)bb * HW * CC;
  float* Cb = C + (size_t)bb * (size_t)MOUT * HW;

  __shared__ unsigned short lA[128 * LP];
  __shared__ unsigned short lB[128 * LP];

  const int tid  = threadIdx.x;
  const int wave = tid >> 6;
  const int lane = tid & 63;
  const int wm   = (wave >> 1) * 64;
  const int wn   = (wave & 1) * 64;
  const int lrow = lane & 15;
  const int quad = lane >> 4;

  // staging map: thread -> (row 0..127, 16-elem half of the 32-wide K slab)
  const int srow = tid >> 1;
  const int scol = (tid & 1) * 16;

  floatx4 acc[4][4];
#pragma unroll
  for (int i = 0; i < 4; i++)
#pragma unroll
    for (int j = 0; j < 4; j++)
      acc[i][j] = (floatx4){0.f, 0.f, 0.f, 0.f};

  const unsigned short* ga = A  + (size_t)(m0 + srow) * CC + scol;
  const unsigned short* gb = Bb + (size_t)(n0 + srow) * CC + scol;
  unsigned short* la = &lA[srow * LP + scol];
  unsigned short* lb = &lB[srow * LP + scol];

  for (int k0 = 0; k0 < CC; k0 += 32) {
    const uint4 a0 = *(const uint4*)(ga + k0);
    const uint4 a1 = *(const uint4*)(ga + k0 + 8);
    const uint4 b0 = *(const uint4*)(gb + k0);
    const uint4 b1 = *(const uint4*)(gb + k0 + 8);
    __syncthreads();
    *(uint4*)la       = a0;
    *(uint4*)(la + 8) = a1;
    *(uint4*)lb       = b0;
    *(uint4*)(lb + 8) = b1;
    __syncthreads();

    short8 af[4], bfr[4];
#pragma unroll
    for (int t = 0; t < 4; t++) {
      af[t]  = *(const short8*)&lA[(wm + t * 16 + lrow) * LP + quad * 8];
      bfr[t] = *(const short8*)&lB[(wn + t * 16 + lrow) * LP + quad * 8];
    }
#pragma unroll
    for (int i = 0; i < 4; i++)
#pragma unroll
      for (int j = 0; j < 4; j++)
        acc[i][j] = __builtin_amdgcn_mfma_f32_16x16x32_bf16(af[i], bfr[j], acc[i][j], 0, 0, 0);
  }

  // epilogue: C/D layout col=lane&15, row=quad*4+r (m89/m91-verified)
#pragma unroll
  for (int i = 0; i < 4; i++) {
    const int mbase = m0 + wm + i * 16 + quad * 4;
#pragma unroll
    for (int j = 0; j < 4; j++) {
      const int n = n0 + wn + j * 16 + lrow;
      float* cp = Cb + (size_t)mbase * HW + n;
#pragma unroll
      for (int r = 0; r < 4; r++)
        cp[(size_t)r * HW] = acc[i][j][r];
    }
  }
}

// ---------------------------------------------------------------------------
extern "C" void kernel_launch(void* const* d_in, const int* in_sizes, int n_in,
                              void* d_out, int out_size, void* d_ws, size_t ws_size,
                              hipStream_t stream)
{
  const float* refer = (const float*)d_in[0];
  const float* sup   = (const float*)d_in[1];
  const float* woff  = (const float*)d_in[2];
  const float* boff  = (const float*)d_in[3];
  const float* wdef  = (const float*)d_in[4];
  float* out = (float*)d_out;

  // workspace layout: [offsets 512KB][w_def bf16 4MB][S_t bf16 32MB] ~= 36.7MB
  char* ws = (char*)d_ws;
  float* off            = (float*)ws;
  unsigned short* wdefb = (unsigned short*)(ws + (512u << 10));
  unsigned short* St    = (unsigned short*)(ws + (512u << 10) + (4u << 20));

  hipMemsetAsync(off, 0, (size_t)NB * 2 * HW * sizeof(float), stream);
  conv_off<<<dim3(8, 8, NB), 256, 0, stream>>>(refer, sup, woff, off);
  cvt_bf16<<<dim3((MOUT * CC / 4 + 255) / 256), 256, 0, stream>>>(wdef, wdefb, MOUT * CC / 4);
  sample_kern<<<dim3(HH, NB), 256, 0, stream>>>(sup, off, boff, St);
  gemm_bt<<<dim3(HW / 128, MOUT / 128, NB), 256, 0, stream>>>(wdefb, St, out);
}

// Round 4
// 455.186 us; speedup vs baseline: 1.6862x; 1.6862x over previous
//
#include <hip/hip_runtime.h>

#define CC   1024
#define C2   2048
#define HH   64
#define WW   64
#define HW   4096
#define MOUT 2048
#define NB   4
#define LP   40   // GEMM LDS pitch in bf16 elems (80B: 16B-aligned, 2-way bank alias = free)

typedef short  short8  __attribute__((ext_vector_type(8)));
typedef float  floatx4 __attribute__((ext_vector_type(4)));

static __device__ __forceinline__ unsigned short f2bf(float f) {
  unsigned int u = __builtin_bit_cast(unsigned int, f);
  u = u + 0x7FFFu + ((u >> 16) & 1u);   // RNE truncate to bf16
  return (unsigned short)(u >> 16);
}

// ---------------------------------------------------------------------------
// Kernel 1: 3x3 conv (2048 -> 2 ch), SAME pad. Barrier-free: one wave owns 2
// output rows, lane = column, column taps via __shfl, weights scalarized.
// BUGFIX vs r2/r3: __shfl must be executed by ALL lanes (ds_bpermute from an
// exec-masked-off source lane is UNDEFINED). Shuffle unconditionally with a
// wrapped index, then select the pad-zero — never mask off the source lane.
// Grid: 32 channel-chunks (x64 ch) x 8 row-tiles x B. atomicAdd reduction.
// ---------------------------------------------------------------------------
__global__ __launch_bounds__(256)
void conv_off(const float* __restrict__ refer, const float* __restrict__ sup,
              const float* __restrict__ woff, float* __restrict__ off)
{
  const int cz = blockIdx.x;             // channel chunk: [cz*64, +64)
  const int ry = blockIdx.y;             // row tile: 8 rows
  const int b  = blockIdx.z;
  const int wv = threadIdx.x >> 6;       // wave 0..3 -> 2 rows each
  const int w  = threadIdx.x & 63;       // column
  const int h0 = ry * 8 + wv * 2;

  float a00 = 0.f, a01 = 0.f, a10 = 0.f, a11 = 0.f;
  const int cbase = cz * 64;

  for (int ci = 0; ci < 64; ci++) {
    const int cc = cbase + ci;
    const float* plane = (cc < CC) ? (refer + ((size_t)b * CC + cc) * HW)
                                   : (sup   + ((size_t)b * CC + (cc - CC)) * HW);
    float r[4];
#pragma unroll
    for (int j = 0; j < 4; j++) {
      const int gy = h0 - 1 + j;                 // wave-uniform bounds check
      r[j] = (gy >= 0 && gy < HH) ? plane[gy * WW + w] : 0.f;
    }
    float lft[4], rgt[4];
#pragma unroll
    for (int j = 0; j < 4; j++) {
      const float tl = __shfl(r[j], (w - 1) & 63, 64);   // all lanes active
      const float tr = __shfl(r[j], (w + 1) & 63, 64);   // all lanes active
      lft[j] = (w == 0)  ? 0.f : tl;
      rgt[j] = (w == 63) ? 0.f : tr;
    }
    const float* wp0 = woff + (size_t)cc * 9;          // o=0 (dy)
    const float* wp1 = woff + (size_t)(C2 + cc) * 9;   // o=1 (dx)
#pragma unroll
    for (int ky = 0; ky < 3; ky++) {
      const float w00 = wp0[ky * 3 + 0], w01 = wp0[ky * 3 + 1], w02 = wp0[ky * 3 + 2];
      const float w10 = wp1[ky * 3 + 0], w11 = wp1[ky * 3 + 1], w12 = wp1[ky * 3 + 2];
      a00 += lft[ky]     * w00 + r[ky]     * w01 + rgt[ky]     * w02;
      a01 += lft[ky]     * w10 + r[ky]     * w11 + rgt[ky]     * w12;
      a10 += lft[ky + 1] * w00 + r[ky + 1] * w01 + rgt[ky + 1] * w02;
      a11 += lft[ky + 1] * w10 + r[ky + 1] * w11 + rgt[ky + 1] * w12;
    }
  }

  atomicAdd(&off[((b * 2 + 0) * HH + h0) * WW + w],     a00);
  atomicAdd(&off[((b * 2 + 1) * HH + h0) * WW + w],     a01);
  atomicAdd(&off[((b * 2 + 0) * HH + h0 + 1) * WW + w], a10);
  atomicAdd(&off[((b * 2 + 1) * HH + h0 + 1) * WW + w], a11);
}

// ---------------------------------------------------------------------------
// Kernel 2: fp32 -> bf16 convert for w_def
// ---------------------------------------------------------------------------
__global__ __launch_bounds__(256)
void cvt_bf16(const float* __restrict__ src, unsigned short* __restrict__ dst, int n4)
{
  const int i = blockIdx.x * 256 + threadIdx.x;
  if (i < n4) {
    const float4 f = ((const float4*)src)[i];
    ushort4 u;
    u.x = f2bf(f.x); u.y = f2bf(f.y); u.z = f2bf(f.z); u.w = f2bf(f.w);
    ((ushort4*)dst)[i] = u;
  }
}

// ---------------------------------------------------------------------------
// Kernel 3: bilinear deform-sample sup_feat, zero pad outside.
// Writes S_t[b][l][c] bf16 (GEMM's B^T layout) via LDS transpose.
// ---------------------------------------------------------------------------
__global__ __launch_bounds__(256)
void sample_kern(const float* __restrict__ sup, const float* __restrict__ off,
                 const float* __restrict__ boff, unsigned short* __restrict__ St)
{
  const int h   = blockIdx.x;
  const int b   = blockIdx.y;
  const int tid = threadIdx.x;

  __shared__ float swy[64], swx[64];
  __shared__ int   sy0[64], sx0[64];
  __shared__ unsigned short tile[64 * 68];   // [c][l], pitch 68

  if (tid < 64) {
    const float dy = off[((b * 2 + 0) * HH + h) * WW + tid] + boff[0];
    const float dx = off[((b * 2 + 1) * HH + h) * WW + tid] + boff[1];
    const float py = dy + (float)h;
    const float px = dx + (float)tid;
    const float y0f = floorf(py), x0f = floorf(px);
    sy0[tid] = (int)y0f;  sx0[tid] = (int)x0f;
    swy[tid] = py - y0f;  swx[tid] = px - x0f;
  }
  __syncthreads();

  const int l   = tid & 63;
  const int cs0 = tid >> 6;
  const int y0 = sy0[l], x0 = sx0[l];
  const int y1 = y0 + 1, x1 = x0 + 1;
  const float wy1 = swy[l], wx1 = swx[l];
  const float wy0 = 1.f - wy1, wx0 = 1.f - wx1;
  const float vy0 = (y0 >= 0 && y0 < HH) ? 1.f : 0.f;
  const float vy1 = (y1 >= 0 && y1 < HH) ? 1.f : 0.f;
  const float vx0 = (x0 >= 0 && x0 < WW) ? 1.f : 0.f;
  const float vx1 = (x1 >= 0 && x1 < WW) ? 1.f : 0.f;
  const int cy0 = min(max(y0, 0), HH - 1), cy1 = min(max(y1, 0), HH - 1);
  const int cx0 = min(max(x0, 0), WW - 1), cx1 = min(max(x1, 0), WW - 1);
  const int i00 = cy0 * WW + cx0, i01 = cy0 * WW + cx1;
  const int i10 = cy1 * WW + cx0, i11 = cy1 * WW + cx1;
  const float w00 = wy0 * wx0 * vy0 * vx0;
  const float w01 = wy0 * wx1 * vy0 * vx1;
  const float w10 = wy1 * wx0 * vy1 * vx0;
  const float w11 = wy1 * wx1 * vy1 * vx1;

  const int cq  = tid & 15;
  const int ls0 = tid >> 4;
  unsigned short* stb = St + ((size_t)b * HW + h * 64) * CC;

  for (int ct = 0; ct < 16; ct++) {
    const int cb = ct * 64;
    for (int cs = cs0; cs < 64; cs += 4) {
      const float* sp = sup + ((size_t)b * CC + cb + cs) * HW;
      const float v = w00 * sp[i00] + w01 * sp[i01] + w10 * sp[i10] + w11 * sp[i11];
      tile[cs * 68 + l] = f2bf(v);
    }
    __syncthreads();
    for (int ls = ls0; ls < 64; ls += 16) {
      ushort4 pk;
      pk.x = tile[(cq * 4 + 0) * 68 + ls];
      pk.y = tile[(cq * 4 + 1) * 68 + ls];
      pk.z = tile[(cq * 4 + 2) * 68 + ls];
      pk.w = tile[(cq * 4 + 3) * 68 + ls];
      *(ushort4*)&stb[(size_t)ls * CC + cb + cq * 4] = pk;
    }
    __syncthreads();
  }
}

// ---------------------------------------------------------------------------
// Kernel 4: bf16 MFMA GEMM (round-1 VERIFIED version, byte-identical).
// out[b][m][n] = sum_k A[m][k] * Bt[b][n][k].
// 128x128 block tile, BK=32, 4 waves each 64x64 (4x4 of 16x16x32 MFMA).
// ---------------------------------------------------------------------------
__global__ __launch_bounds__(256)
void gemm_bt(const unsigned short* __restrict__ A,
             const unsigned short* __restrict__ Bt,
             float* __restrict__ C)
{
  const int bb = blockIdx.z;
  const int n0 = blockIdx.x * 128;
  const int m0 = blockIdx.y * 128;
  const unsigned short* Bb = Bt + (size_t)bb * HW * CC;
  float* Cb = C + (size_t)bb * (size_t)MOUT * HW;

  __shared__ unsigned short lA[128 * LP];
  __shared__ unsigned short lB[128 * LP];

  const int tid  = threadIdx.x;
  const int wave = tid >> 6;
  const int lane = tid & 63;
  const int wm   = (wave >> 1) * 64;
  const int wn   = (wave & 1) * 64;
  const int lrow = lane & 15;
  const int quad = lane >> 4;

  // staging map: thread -> (row 0..127, 16-elem half of the 32-wide K slab)
  const int srow = tid >> 1;
  const int scol = (tid & 1) * 16;

  floatx4 acc[4][4];
#pragma unroll
  for (int i = 0; i < 4; i++)
#pragma unroll
    for (int j = 0; j < 4; j++)
      acc[i][j] = (floatx4){0.f, 0.f, 0.f, 0.f};

  const unsigned short* ga = A  + (size_t)(m0 + srow) * CC + scol;
  const unsigned short* gb = Bb + (size_t)(n0 + srow) * CC + scol;
  unsigned short* la = &lA[srow * LP + scol];
  unsigned short* lb = &lB[srow * LP + scol];

  for (int k0 = 0; k0 < CC; k0 += 32) {
    const uint4 a0 = *(const uint4*)(ga + k0);
    const uint4 a1 = *(const uint4*)(ga + k0 + 8);
    const uint4 b0 = *(const uint4*)(gb + k0);
    const uint4 b1 = *(const uint4*)(gb + k0 + 8);
    __syncthreads();
    *(uint4*)la       = a0;
    *(uint4*)(la + 8) = a1;
    *(uint4*)lb       = b0;
    *(uint4*)(lb + 8) = b1;
    __syncthreads();

    short8 af[4], bfr[4];
#pragma unroll
    for (int t = 0; t < 4; t++) {
      af[t]  = *(const short8*)&lA[(wm + t * 16 + lrow) * LP + quad * 8];
      bfr[t] = *(const short8*)&lB[(wn + t * 16 + lrow) * LP + quad * 8];
    }
#pragma unroll
    for (int i = 0; i < 4; i++)
#pragma unroll
      for (int j = 0; j < 4; j++)
        acc[i][j] = __builtin_amdgcn_mfma_f32_16x16x32_bf16(af[i], bfr[j], acc[i][j], 0, 0, 0);
  }

  // epilogue: C/D layout col=lane&15, row=quad*4+r (m89/m91-verified)
#pragma unroll
  for (int i = 0; i < 4; i++) {
    const int mbase = m0 + wm + i * 16 + quad * 4;
#pragma unroll
    for (int j = 0; j < 4; j++) {
      const int n = n0 + wn + j * 16 + lrow;
      float* cp = Cb + (size_t)mbase * HW + n;
#pragma unroll
      for (int r = 0; r < 4; r++)
        cp[(size_t)r * HW] = acc[i][j][r];
    }
  }
}

// ---------------------------------------------------------------------------
extern "C" void kernel_launch(void* const* d_in, const int* in_sizes, int n_in,
                              void* d_out, int out_size, void* d_ws, size_t ws_size,
                              hipStream_t stream)
{
  const float* refer = (const float*)d_in[0];
  const float* sup   = (const float*)d_in[1];
  const float* woff  = (const float*)d_in[2];
  const float* boff  = (const float*)d_in[3];
  const float* wdef  = (const float*)d_in[4];
  float* out = (float*)d_out;

  // workspace: [offsets 512KB][w_def bf16 4MB][S_t bf16 32MB]
  char* ws = (char*)d_ws;
  float* off            = (float*)ws;
  unsigned short* wdefb = (unsigned short*)(ws + (512u << 10));
  unsigned short* St    = (unsigned short*)(ws + (512u << 10) + (4u << 20));

  hipMemsetAsync(off, 0, (size_t)NB * 2 * HW * sizeof(float), stream);
  conv_off<<<dim3(32, 8, NB), 256, 0, stream>>>(refer, sup, woff, off);
  cvt_bf16<<<dim3((MOUT * CC / 4 + 255) / 256), 256, 0, stream>>>(wdef, wdefb, MOUT * CC / 4);
  sample_kern<<<dim3(HH, NB), 256, 0, stream>>>(sup, off, boff, St);
  gemm_bt<<<dim3(HW / 128, MOUT / 128, NB), 256, 0, stream>>>(wdefb, St, out);
}

// Round 5
// 401.102 us; speedup vs baseline: 1.9135x; 1.1348x over previous
//
#include <hip/hip_runtime.h>

#define CC   1024
#define C2   2048
#define HH   64
#define WW   64
#define HW   4096
#define MOUT 2048
#define NB   4

typedef short  short8  __attribute__((ext_vector_type(8)));
typedef float  floatx4 __attribute__((ext_vector_type(4)));

static __device__ __forceinline__ unsigned short f2bf(float f) {
  unsigned int u = __builtin_bit_cast(unsigned int, f);
  u = u + 0x7FFFu + ((u >> 16) & 1u);   // RNE truncate to bf16
  return (unsigned short)(u >> 16);
}

// async 16B global -> LDS (DMA: wave-uniform LDS base + lane*16)
static __device__ __forceinline__ void glds16(const unsigned short* g, unsigned short* l) {
  __builtin_amdgcn_global_load_lds(
      (const __attribute__((address_space(1))) void*)g,
      (__attribute__((address_space(3))) void*)l, 16, 0, 0);
}

// ---------------------------------------------------------------------------
// Kernel 1: 3x3 conv (2048 -> 2 ch), SAME pad. Barrier-free shfl version
// (r4 VERIFIED — shuffle executed by all lanes, pad selected after).
// ---------------------------------------------------------------------------
__global__ __launch_bounds__(256)
void conv_off(const float* __restrict__ refer, const float* __restrict__ sup,
              const float* __restrict__ woff, float* __restrict__ off)
{
  const int cz = blockIdx.x;             // channel chunk: [cz*64, +64)
  const int ry = blockIdx.y;             // row tile: 8 rows
  const int b  = blockIdx.z;
  const int wv = threadIdx.x >> 6;       // wave 0..3 -> 2 rows each
  const int w  = threadIdx.x & 63;       // column
  const int h0 = ry * 8 + wv * 2;

  float a00 = 0.f, a01 = 0.f, a10 = 0.f, a11 = 0.f;
  const int cbase = cz * 64;

  for (int ci = 0; ci < 64; ci++) {
    const int cc = cbase + ci;
    const float* plane = (cc < CC) ? (refer + ((size_t)b * CC + cc) * HW)
                                   : (sup   + ((size_t)b * CC + (cc - CC)) * HW);
    float r[4];
#pragma unroll
    for (int j = 0; j < 4; j++) {
      const int gy = h0 - 1 + j;                 // wave-uniform bounds check
      r[j] = (gy >= 0 && gy < HH) ? plane[gy * WW + w] : 0.f;
    }
    float lft[4], rgt[4];
#pragma unroll
    for (int j = 0; j < 4; j++) {
      const float tl = __shfl(r[j], (w - 1) & 63, 64);   // all lanes active
      const float tr = __shfl(r[j], (w + 1) & 63, 64);   // all lanes active
      lft[j] = (w == 0)  ? 0.f : tl;
      rgt[j] = (w == 63) ? 0.f : tr;
    }
    const float* wp0 = woff + (size_t)cc * 9;          // o=0 (dy)
    const float* wp1 = woff + (size_t)(C2 + cc) * 9;   // o=1 (dx)
#pragma unroll
    for (int ky = 0; ky < 3; ky++) {
      const float w00 = wp0[ky * 3 + 0], w01 = wp0[ky * 3 + 1], w02 = wp0[ky * 3 + 2];
      const float w10 = wp1[ky * 3 + 0], w11 = wp1[ky * 3 + 1], w12 = wp1[ky * 3 + 2];
      a00 += lft[ky]     * w00 + r[ky]     * w01 + rgt[ky]     * w02;
      a01 += lft[ky]     * w10 + r[ky]     * w11 + rgt[ky]     * w12;
      a10 += lft[ky + 1] * w00 + r[ky + 1] * w01 + rgt[ky + 1] * w02;
      a11 += lft[ky + 1] * w10 + r[ky + 1] * w11 + rgt[ky + 1] * w12;
    }
  }

  atomicAdd(&off[((b * 2 + 0) * HH + h0) * WW + w],     a00);
  atomicAdd(&off[((b * 2 + 1) * HH + h0) * WW + w],     a01);
  atomicAdd(&off[((b * 2 + 0) * HH + h0 + 1) * WW + w], a10);
  atomicAdd(&off[((b * 2 + 1) * HH + h0 + 1) * WW + w], a11);
}

// ---------------------------------------------------------------------------
// Kernel 2: fp32 -> bf16 convert for w_def
// ---------------------------------------------------------------------------
__global__ __launch_bounds__(256)
void cvt_bf16(const float* __restrict__ src, unsigned short* __restrict__ dst, int n4)
{
  const int i = blockIdx.x * 256 + threadIdx.x;
  if (i < n4) {
    const float4 f = ((const float4*)src)[i];
    ushort4 u;
    u.x = f2bf(f.x); u.y = f2bf(f.y); u.z = f2bf(f.z); u.w = f2bf(f.w);
    ((ushort4*)dst)[i] = u;
  }
}

// ---------------------------------------------------------------------------
// Kernel 3: bilinear deform-sample. R5 change: channel-tile loop moved to
// blockIdx.y (16x more blocks -> 8 blocks/CU, latency hidden; 2 barriers
// per block instead of 32). Writes S_t[b][l][c] bf16 via LDS transpose.
// ---------------------------------------------------------------------------
__global__ __launch_bounds__(256)
void sample_kern(const float* __restrict__ sup, const float* __restrict__ off,
                 const float* __restrict__ boff, unsigned short* __restrict__ St)
{
  const int h   = blockIdx.x;            // image row
  const int ct  = blockIdx.y;            // channel tile: [ct*64, +64)
  const int b   = blockIdx.z;
  const int tid = threadIdx.x;

  __shared__ float swy[64], swx[64];
  __shared__ int   sy0[64], sx0[64];
  __shared__ unsigned short tile[64 * 68];   // [c][l], pitch 68

  if (tid < 64) {
    const float dy = off[((b * 2 + 0) * HH + h) * WW + tid] + boff[0];
    const float dx = off[((b * 2 + 1) * HH + h) * WW + tid] + boff[1];
    const float py = dy + (float)h;
    const float px = dx + (float)tid;
    const float y0f = floorf(py), x0f = floorf(px);
    sy0[tid] = (int)y0f;  sx0[tid] = (int)x0f;
    swy[tid] = py - y0f;  swx[tid] = px - x0f;
  }
  __syncthreads();

  const int l   = tid & 63;
  const int cs0 = tid >> 6;
  const int y0 = sy0[l], x0 = sx0[l];
  const int y1 = y0 + 1, x1 = x0 + 1;
  const float wy1 = swy[l], wx1 = swx[l];
  const float wy0 = 1.f - wy1, wx0 = 1.f - wx1;
  const float vy0 = (y0 >= 0 && y0 < HH) ? 1.f : 0.f;
  const float vy1 = (y1 >= 0 && y1 < HH) ? 1.f : 0.f;
  const float vx0 = (x0 >= 0 && x0 < WW) ? 1.f : 0.f;
  const float vx1 = (x1 >= 0 && x1 < WW) ? 1.f : 0.f;
  const int cy0 = min(max(y0, 0), HH - 1), cy1 = min(max(y1, 0), HH - 1);
  const int cx0 = min(max(x0, 0), WW - 1), cx1 = min(max(x1, 0), WW - 1);
  const int i00 = cy0 * WW + cx0, i01 = cy0 * WW + cx1;
  const int i10 = cy1 * WW + cx0, i11 = cy1 * WW + cx1;
  const float w00 = wy0 * wx0 * vy0 * vx0;
  const float w01 = wy0 * wx1 * vy0 * vx1;
  const float w10 = wy1 * wx0 * vy1 * vx0;
  const float w11 = wy1 * wx1 * vy1 * vx1;

  const int cb = ct * 64;
  // phase A: lanes across l (near-coalesced gathers), write tile[c][l]
  for (int cs = cs0; cs < 64; cs += 4) {
    const float* sp = sup + ((size_t)b * CC + cb + cs) * HW;
    const float v = w00 * sp[i00] + w01 * sp[i01] + w10 * sp[i10] + w11 * sp[i11];
    tile[cs * 68 + l] = f2bf(v);
  }
  __syncthreads();
  // phase B: lanes across c, coalesced ushort4 stores to S_t[l][c]
  const int cq  = tid & 15;
  const int ls0 = tid >> 4;
  unsigned short* stb = St + ((size_t)b * HW + h * 64) * CC;
  for (int ls = ls0; ls < 64; ls += 16) {
    ushort4 pk;
    pk.x = tile[(cq * 4 + 0) * 68 + ls];
    pk.y = tile[(cq * 4 + 1) * 68 + ls];
    pk.z = tile[(cq * 4 + 2) * 68 + ls];
    pk.w = tile[(cq * 4 + 3) * 68 + ls];
    *(ushort4*)&stb[(size_t)ls * CC + cb + cq * 4] = pk;
  }
}

// ---------------------------------------------------------------------------
// Kernel 4: bf16 MFMA GEMM, m97-style (round-2 design, exonerated by the
// r2/r3 identical-absmax evidence). out[b][m][n] = sum_k A[m][k]*Bt[b][n][k].
// 128x128 tile, BK=64, global_load_lds width=16, XOR-swizzled LDS
// (LDS[r][s] holds G[r][k0+(s^(r&7))*8], 128B rows) -> ds_read_b128 conflict-free.
// ---------------------------------------------------------------------------
__global__ __launch_bounds__(256)
void gemm_bt(const unsigned short* __restrict__ A,
             const unsigned short* __restrict__ Bt,
             float* __restrict__ C)
{
  const int bb = blockIdx.z;
  const int n0 = blockIdx.x * 128;
  const int m0 = blockIdx.y * 128;
  const unsigned short* Bb = Bt + (size_t)bb * HW * CC;
  float* Cb = C + (size_t)bb * (size_t)MOUT * HW;

  __shared__ __align__(16) unsigned short lA[128 * 64];   // 16 KB, rows of 64 elems (128B)
  __shared__ __align__(16) unsigned short lB[128 * 64];

  const int tid  = threadIdx.x;
  const int wave = tid >> 6;
  const int lane = tid & 63;
  const int wm   = (wave >> 1) * 64;
  const int wn   = (wave & 1) * 64;
  const int lrow = lane & 15;
  const int quad = lane >> 4;

  // staging: wave covers rows [wave*32, +32) in 4 issues of 8 rows.
  // lane -> row-in-group g8 = lane>>3, slab s = lane&7; source slab swizzled
  // s_data = s ^ (row&7) = s ^ g8 (row group base is 8-aligned).
  const int g8 = lane >> 3;
  const int s8 = (lane & 7) ^ g8;
  const unsigned short* gA = A  + (size_t)(m0 + wave * 32 + g8) * CC + s8 * 8;
  const unsigned short* gB = Bb + (size_t)(n0 + wave * 32 + g8) * CC + s8 * 8;

  floatx4 acc[4][4];
#pragma unroll
  for (int i = 0; i < 4; i++)
#pragma unroll
    for (int j = 0; j < 4; j++)
      acc[i][j] = (floatx4){0.f, 0.f, 0.f, 0.f};

  for (int k0 = 0; k0 < CC; k0 += 64) {
    __syncthreads();                       // prev iter's LDS reads done
#pragma unroll
    for (int q = 0; q < 4; q++) {
      glds16(gA + (size_t)q * 8 * CC + k0, &lA[(wave * 32 + q * 8) * 64]);
      glds16(gB + (size_t)q * 8 * CC + k0, &lB[(wave * 32 + q * 8) * 64]);
    }
    __syncthreads();                       // staging visible (vmcnt drain @ barrier)

#pragma unroll
    for (int ks = 0; ks < 2; ks++) {
      short8 af[4], bfr[4];
#pragma unroll
      for (int t = 0; t < 4; t++) {
        const int sw = ((ks * 4 + quad) ^ (lrow & 7)) * 8;   // swizzled slab offset (elems)
        af[t]  = *(const short8*)&lA[(wm + t * 16 + lrow) * 64 + sw];
        bfr[t] = *(const short8*)&lB[(wn + t * 16 + lrow) * 64 + sw];
      }
#pragma unroll
      for (int i = 0; i < 4; i++)
#pragma unroll
        for (int j = 0; j < 4; j++)
          acc[i][j] = __builtin_amdgcn_mfma_f32_16x16x32_bf16(af[i], bfr[j], acc[i][j], 0, 0, 0);
    }
  }

  // epilogue: C/D layout col=lane&15, row=quad*4+r (m89/m91-verified)
#pragma unroll
  for (int i = 0; i < 4; i++) {
    const int mbase = m0 + wm + i * 16 + quad * 4;
#pragma unroll
    for (int j = 0; j < 4; j++) {
      const int n = n0 + wn + j * 16 + lrow;
      float* cp = Cb + (size_t)mbase * HW + n;
#pragma unroll
      for (int r = 0; r < 4; r++)
        cp[(size_t)r * HW] = acc[i][j][r];
    }
  }
}

// ---------------------------------------------------------------------------
extern "C" void kernel_launch(void* const* d_in, const int* in_sizes, int n_in,
                              void* d_out, int out_size, void* d_ws, size_t ws_size,
                              hipStream_t stream)
{
  const float* refer = (const float*)d_in[0];
  const float* sup   = (const float*)d_in[1];
  const float* woff  = (const float*)d_in[2];
  const float* boff  = (const float*)d_in[3];
  const float* wdef  = (const float*)d_in[4];
  float* out = (float*)d_out;

  // workspace: [offsets 512KB][w_def bf16 4MB][S_t bf16 32MB]
  char* ws = (char*)d_ws;
  float* off            = (float*)ws;
  unsigned short* wdefb = (unsigned short*)(ws + (512u << 10));
  unsigned short* St    = (unsigned short*)(ws + (512u << 10) + (4u << 20));

  hipMemsetAsync(off, 0, (size_t)NB * 2 * HW * sizeof(float), stream);
  conv_off<<<dim3(32, 8, NB), 256, 0, stream>>>(refer, sup, woff, off);
  cvt_bf16<<<dim3((MOUT * CC / 4 + 255) / 256), 256, 0, stream>>>(wdef, wdefb, MOUT * CC / 4);
  sample_kern<<<dim3(HH, 16, NB), 256, 0, stream>>>(sup, off, boff, St);
  gemm_bt<<<dim3(HW / 128, MOUT / 128, NB), 256, 0, stream>>>(wdefb, St, out);
}

// Round 6
// 372.217 us; speedup vs baseline: 2.0620x; 1.0776x over previous
//
#include <hip/hip_runtime.h>

#define CC   1024
#define C2   2048
#define HH   64
#define WW   64
#define HW   4096
#define MOUT 2048
#define NB   4

typedef short  short8  __attribute__((ext_vector_type(8)));
typedef float  floatx4 __attribute__((ext_vector_type(4)));

static __device__ __forceinline__ unsigned short f2bf(float f) {
  unsigned int u = __builtin_bit_cast(unsigned int, f);
  u = u + 0x7FFFu + ((u >> 16) & 1u);   // RNE truncate to bf16
  return (unsigned short)(u >> 16);
}

// async 16B global -> LDS (DMA: wave-uniform LDS base + lane*16)
static __device__ __forceinline__ void glds16(const unsigned short* g, unsigned short* l) {
  __builtin_amdgcn_global_load_lds(
      (const __attribute__((address_space(1))) void*)g,
      (__attribute__((address_space(3))) void*)l, 16, 0, 0);
}

// ---------------------------------------------------------------------------
// Kernel 1: 3x3 conv (2048 -> 2 ch), SAME pad. R6: 64 chunks x 32 channels
// (2048 blocks -> 8 blocks/CU -> 32 waves/CU) + explicit register prefetch
// pipeline (load ci+1's rows before computing ci). Chunk is uniformly
// refer-or-sup (32 | 1024), so base pointer is hoisted. shfl executed by all
// lanes (r4 fix). atomicAdd reduction into zeroed off buffer.
// ---------------------------------------------------------------------------
__global__ __launch_bounds__(256)
void conv_off(const float* __restrict__ refer, const float* __restrict__ sup,
              const float* __restrict__ woff, float* __restrict__ off)
{
  const int cz = blockIdx.x;             // channel chunk: 32 channels
  const int ry = blockIdx.y;             // row tile: 8 rows
  const int b  = blockIdx.z;
  const int wv = threadIdx.x >> 6;       // wave 0..3 -> 2 rows each
  const int w  = threadIdx.x & 63;       // column
  const int h0 = ry * 8 + wv * 2;

  const int cc0 = cz * 32;               // global input-channel base
  const float* basep = (cz < 32)
      ? refer + ((size_t)b * CC + cc0) * HW
      : sup   + ((size_t)b * CC + (cc0 - CC)) * HW;

  const int gy0 = h0 - 1;
  const bool top_ok = (gy0 >= 0);
  const bool bot_ok = (h0 + 2 < HH);

  float a00 = 0.f, a01 = 0.f, a10 = 0.f, a11 = 0.f;

  // software pipeline: rn holds channel ci's rows entering iteration ci
  float rn[4];
#pragma unroll
  for (int j = 0; j < 4; j++) {
    const bool ok = (j == 0) ? top_ok : (j == 3) ? bot_ok : true;
    rn[j] = ok ? basep[(gy0 + j) * WW + w] : 0.f;
  }

  for (int ci = 0; ci < 32; ci++) {
    float rc[4];
#pragma unroll
    for (int j = 0; j < 4; j++) rc[j] = rn[j];

    if (ci < 31) {
      const float* pn = basep + (size_t)(ci + 1) * HW;
#pragma unroll
      for (int j = 0; j < 4; j++) {
        const bool ok = (j == 0) ? top_ok : (j == 3) ? bot_ok : true;
        rn[j] = ok ? pn[(gy0 + j) * WW + w] : 0.f;
      }
    }

    float lft[4], rgt[4];
#pragma unroll
    for (int j = 0; j < 4; j++) {
      const float tl = __shfl(rc[j], (w - 1) & 63, 64);   // all lanes active
      const float tr = __shfl(rc[j], (w + 1) & 63, 64);
      lft[j] = (w == 0)  ? 0.f : tl;
      rgt[j] = (w == 63) ? 0.f : tr;
    }

    const int cc = cc0 + ci;
    const float* wp0 = woff + (size_t)cc * 9;          // o=0 (dy)
    const float* wp1 = woff + (size_t)(C2 + cc) * 9;   // o=1 (dx)
#pragma unroll
    for (int ky = 0; ky < 3; ky++) {
      const float w00 = wp0[ky * 3 + 0], w01 = wp0[ky * 3 + 1], w02 = wp0[ky * 3 + 2];
      const float w10 = wp1[ky * 3 + 0], w11 = wp1[ky * 3 + 1], w12 = wp1[ky * 3 + 2];
      a00 += lft[ky]     * w00 + rc[ky]     * w01 + rgt[ky]     * w02;
      a01 += lft[ky]     * w10 + rc[ky]     * w11 + rgt[ky]     * w12;
      a10 += lft[ky + 1] * w00 + rc[ky + 1] * w01 + rgt[ky + 1] * w02;
      a11 += lft[ky + 1] * w10 + rc[ky + 1] * w11 + rgt[ky + 1] * w12;
    }
  }

  atomicAdd(&off[((b * 2 + 0) * HH + h0) * WW + w],     a00);
  atomicAdd(&off[((b * 2 + 1) * HH + h0) * WW + w],     a01);
  atomicAdd(&off[((b * 2 + 0) * HH + h0 + 1) * WW + w], a10);
  atomicAdd(&off[((b * 2 + 1) * HH + h0 + 1) * WW + w], a11);
}

// ---------------------------------------------------------------------------
// Kernel 2: fp32 -> bf16 convert for w_def
// ---------------------------------------------------------------------------
__global__ __launch_bounds__(256)
void cvt_bf16(const float* __restrict__ src, unsigned short* __restrict__ dst, int n4)
{
  const int i = blockIdx.x * 256 + threadIdx.x;
  if (i < n4) {
    const float4 f = ((const float4*)src)[i];
    ushort4 u;
    u.x = f2bf(f.x); u.y = f2bf(f.y); u.z = f2bf(f.z); u.w = f2bf(f.w);
    ((ushort4*)dst)[i] = u;
  }
}

// ---------------------------------------------------------------------------
// Kernel 3: bilinear deform-sample (r5 VERIFIED). Channel tile on blockIdx.y.
// Writes S_t[b][l][c] bf16 via LDS transpose.
// ---------------------------------------------------------------------------
__global__ __launch_bounds__(256)
void sample_kern(const float* __restrict__ sup, const float* __restrict__ off,
                 const float* __restrict__ boff, unsigned short* __restrict__ St)
{
  const int h   = blockIdx.x;            // image row
  const int ct  = blockIdx.y;            // channel tile: [ct*64, +64)
  const int b   = blockIdx.z;
  const int tid = threadIdx.x;

  __shared__ float swy[64], swx[64];
  __shared__ int   sy0[64], sx0[64];
  __shared__ unsigned short tile[64 * 68];   // [c][l], pitch 68

  if (tid < 64) {
    const float dy = off[((b * 2 + 0) * HH + h) * WW + tid] + boff[0];
    const float dx = off[((b * 2 + 1) * HH + h) * WW + tid] + boff[1];
    const float py = dy + (float)h;
    const float px = dx + (float)tid;
    const float y0f = floorf(py), x0f = floorf(px);
    sy0[tid] = (int)y0f;  sx0[tid] = (int)x0f;
    swy[tid] = py - y0f;  swx[tid] = px - x0f;
  }
  __syncthreads();

  const int l   = tid & 63;
  const int cs0 = tid >> 6;
  const int y0 = sy0[l], x0 = sx0[l];
  const int y1 = y0 + 1, x1 = x0 + 1;
  const float wy1 = swy[l], wx1 = swx[l];
  const float wy0 = 1.f - wy1, wx0 = 1.f - wx1;
  const float vy0 = (y0 >= 0 && y0 < HH) ? 1.f : 0.f;
  const float vy1 = (y1 >= 0 && y1 < HH) ? 1.f : 0.f;
  const float vx0 = (x0 >= 0 && x0 < WW) ? 1.f : 0.f;
  const float vx1 = (x1 >= 0 && x1 < WW) ? 1.f : 0.f;
  const int cy0 = min(max(y0, 0), HH - 1), cy1 = min(max(y1, 0), HH - 1);
  const int cx0 = min(max(x0, 0), WW - 1), cx1 = min(max(x1, 0), WW - 1);
  const int i00 = cy0 * WW + cx0, i01 = cy0 * WW + cx1;
  const int i10 = cy1 * WW + cx0, i11 = cy1 * WW + cx1;
  const float w00 = wy0 * wx0 * vy0 * vx0;
  const float w01 = wy0 * wx1 * vy0 * vx1;
  const float w10 = wy1 * wx0 * vy1 * vx0;
  const float w11 = wy1 * wx1 * vy1 * vx1;

  const int cb = ct * 64;
  for (int cs = cs0; cs < 64; cs += 4) {
    const float* sp = sup + ((size_t)b * CC + cb + cs) * HW;
    const float v = w00 * sp[i00] + w01 * sp[i01] + w10 * sp[i10] + w11 * sp[i11];
    tile[cs * 68 + l] = f2bf(v);
  }
  __syncthreads();
  const int cq  = tid & 15;
  const int ls0 = tid >> 4;
  unsigned short* stb = St + ((size_t)b * HW + h * 64) * CC;
  for (int ls = ls0; ls < 64; ls += 16) {
    ushort4 pk;
    pk.x = tile[(cq * 4 + 0) * 68 + ls];
    pk.y = tile[(cq * 4 + 1) * 68 + ls];
    pk.z = tile[(cq * 4 + 2) * 68 + ls];
    pk.w = tile[(cq * 4 + 3) * 68 + ls];
    *(ushort4*)&stb[(size_t)ls * CC + cb + cq * 4] = pk;
  }
}

// ---------------------------------------------------------------------------
// Kernel 4: bf16 MFMA GEMM (r5 VERIFIED, byte-identical). 128x128 tile,
// BK=64, global_load_lds width=16, XOR-swizzled LDS, conflict-free.
// ---------------------------------------------------------------------------
__global__ __launch_bounds__(256)
void gemm_bt(const unsigned short* __restrict__ A,
             const unsigned short* __restrict__ Bt,
             float* __restrict__ C)
{
  const int bb = blockIdx.z;
  const int n0 = blockIdx.x * 128;
  const int m0 = blockIdx.y * 128;
  const unsigned short* Bb = Bt + (size_t)bb * HW * CC;
  float* Cb = C + (size_t)bb * (size_t)MOUT * HW;

  __shared__ __align__(16) unsigned short lA[128 * 64];   // 16 KB, 128B rows
  __shared__ __align__(16) unsigned short lB[128 * 64];

  const int tid  = threadIdx.x;
  const int wave = tid >> 6;
  const int lane = tid & 63;
  const int wm   = (wave >> 1) * 64;
  const int wn   = (wave & 1) * 64;
  const int lrow = lane & 15;
  const int quad = lane >> 4;

  const int g8 = lane >> 3;
  const int s8 = (lane & 7) ^ g8;
  const unsigned short* gA = A  + (size_t)(m0 + wave * 32 + g8) * CC + s8 * 8;
  const unsigned short* gB = Bb + (size_t)(n0 + wave * 32 + g8) * CC + s8 * 8;

  floatx4 acc[4][4];
#pragma unroll
  for (int i = 0; i < 4; i++)
#pragma unroll
    for (int j = 0; j < 4; j++)
      acc[i][j] = (floatx4){0.f, 0.f, 0.f, 0.f};

  for (int k0 = 0; k0 < CC; k0 += 64) {
    __syncthreads();
#pragma unroll
    for (int q = 0; q < 4; q++) {
      glds16(gA + (size_t)q * 8 * CC + k0, &lA[(wave * 32 + q * 8) * 64]);
      glds16(gB + (size_t)q * 8 * CC + k0, &lB[(wave * 32 + q * 8) * 64]);
    }
    __syncthreads();

#pragma unroll
    for (int ks = 0; ks < 2; ks++) {
      short8 af[4], bfr[4];
#pragma unroll
      for (int t = 0; t < 4; t++) {
        const int sw = ((ks * 4 + quad) ^ (lrow & 7)) * 8;
        af[t]  = *(const short8*)&lA[(wm + t * 16 + lrow) * 64 + sw];
        bfr[t] = *(const short8*)&lB[(wn + t * 16 + lrow) * 64 + sw];
      }
#pragma unroll
      for (int i = 0; i < 4; i++)
#pragma unroll
        for (int j = 0; j < 4; j++)
          acc[i][j] = __builtin_amdgcn_mfma_f32_16x16x32_bf16(af[i], bfr[j], acc[i][j], 0, 0, 0);
    }
  }

#pragma unroll
  for (int i = 0; i < 4; i++) {
    const int mbase = m0 + wm + i * 16 + quad * 4;
#pragma unroll
    for (int j = 0; j < 4; j++) {
      const int n = n0 + wn + j * 16 + lrow;
      float* cp = Cb + (size_t)mbase * HW + n;
#pragma unroll
      for (int r = 0; r < 4; r++)
        cp[(size_t)r * HW] = acc[i][j][r];
    }
  }
}

// ---------------------------------------------------------------------------
extern "C" void kernel_launch(void* const* d_in, const int* in_sizes, int n_in,
                              void* d_out, int out_size, void* d_ws, size_t ws_size,
                              hipStream_t stream)
{
  const float* refer = (const float*)d_in[0];
  const float* sup   = (const float*)d_in[1];
  const float* woff  = (const float*)d_in[2];
  const float* boff  = (const float*)d_in[3];
  const float* wdef  = (const float*)d_in[4];
  float* out = (float*)d_out;

  // workspace: [offsets 512KB][w_def bf16 4MB][S_t bf16 32MB]
  char* ws = (char*)d_ws;
  float* off            = (float*)ws;
  unsigned short* wdefb = (unsigned short*)(ws + (512u << 10));
  unsigned short* St    = (unsigned short*)(ws + (512u << 10) + (4u << 20));

  hipMemsetAsync(off, 0, (size_t)NB * 2 * HW * sizeof(float), stream);
  conv_off<<<dim3(64, 8, NB), 256, 0, stream>>>(refer, sup, woff, off);
  cvt_bf16<<<dim3((MOUT * CC / 4 + 255) / 256), 256, 0, stream>>>(wdef, wdefb, MOUT * CC / 4);
  sample_kern<<<dim3(HH, 16, NB), 256, 0, stream>>>(sup, off, boff, St);
  gemm_bt<<<dim3(HW / 128, MOUT / 128, NB), 256, 0, stream>>>(wdefb, St, out);
}